// Round 10
// baseline (86.404 us; speedup 1.0000x reference)
//
#include <hip/hip_runtime.h>

#define NN 4096
#define DIN 512
#define DH 128
#define NH 4
#define L2E 1.44269504f

typedef float f32x4 __attribute__((ext_vector_type(4)));
typedef _Float16 f16x8 __attribute__((ext_vector_type(8)));
typedef _Float16 f16x4 __attribute__((ext_vector_type(4)));
typedef _Float16 f16x2 __attribute__((ext_vector_type(2)));

__device__ __forceinline__ float leaky(float x){ return x > 0.f ? x : 0.2f*x; }
__device__ __forceinline__ f16x2 h2max(f16x2 a, f16x2 b){
  f16x2 r; r[0] = a[0]>b[0]?a[0]:b[0]; r[1] = a[1]>b[1]?a[1]:b[1]; return r;
}

// K0: pack adjacency (0/1 f32) -> bitmask. Coalesced f32x4 loads, LDS nibble pack.
__global__ __launch_bounds__(256) void k_pack(
    const float* __restrict__ adj, unsigned int* __restrict__ bmg)
{
  __shared__ unsigned char nib[2][256];
  const int t = threadIdx.x;
  const size_t base = (size_t)blockIdx.x * 8192;
  #pragma unroll
  for (int it=0; it<8; ++it){
    const size_t fb = base + it*1024;
    f32x4 v = *(const f32x4*)&adj[fb + t*4];
    unsigned nb = (v[0]>0.5f?1u:0u)|(v[1]>0.5f?2u:0u)|(v[2]>0.5f?4u:0u)|(v[3]>0.5f?8u:0u);
    const int buf = it&1;
    nib[buf][t] = (unsigned char)nb;
    __syncthreads();
    if (t < 32){
      unsigned long long x = *(const unsigned long long*)&nib[buf][t*8];
      x &= 0x0F0F0F0F0F0F0F0FULL;
      x = (x | (x>>4))  & 0x00FF00FF00FF00FFULL;
      x = (x | (x>>8))  & 0x0000FFFF0000FFFFULL;
      x = (x | (x>>16));
      bmg[fb/32 + t] = (unsigned int)x;
    }
  }
}

// K1: featsT[h][e][i] = sum_d X[i][d]*Kw[h][d][e]  (f16 out) + a_s/a_n row dots
__global__ __launch_bounds__(256) void k_gemm1(
    const float* __restrict__ X, const float* __restrict__ Kw,
    const float* __restrict__ attn_s, const float* __restrict__ attn_n,
    _Float16* __restrict__ featsT, float* __restrict__ a_s, float* __restrict__ a_n)
{
  const int it = blockIdx.x, h = blockIdx.y;
  const int i0 = it*64;
  const int t = threadIdx.x, w = t>>6, lane = t&63;
  const int eoff = (w>>1)*64, ioff = (w&1)*32;
  const int lg = lane>>4, li = lane&15;

  __shared__ _Float16 KT[128][40];
  __shared__ _Float16 XT[64][40];
  __shared__ float red_s[2][2][2][16];
  __shared__ float red_n[2][2][2][16];

  f32x4 acc[4][2] = {};

  for (int ks=0; ks<16; ++ks){
    const int d0 = ks*32;
    __syncthreads();
    #pragma unroll
    for (int q=0;q<4;q++){
      int f = t + 256*q;
      int e = f & 127, dg = (f>>7)*4;
      f16x4 hv;
      #pragma unroll
      for (int k=0;k<4;k++)
        hv[k] = (_Float16)Kw[(h*DIN + d0 + dg + k)*DH + e];
      *(f16x4*)&KT[e][dg] = hv;
    }
    #pragma unroll
    for (int q=0;q<2;q++){
      int f = t + 256*q;
      int i = f>>3, s = (f&7)*4;
      f32x4 v = *(const f32x4*)&X[(i0+i)*DIN + d0 + s];
      f16x4 hv; hv[0]=(_Float16)v[0]; hv[1]=(_Float16)v[1];
      hv[2]=(_Float16)v[2]; hv[3]=(_Float16)v[3];
      *(f16x4*)&XT[i][s] = hv;
    }
    __syncthreads();
    f16x8 af[4], bf[2];
    #pragma unroll
    for (int ef=0; ef<4; ++ef) af[ef] = *(const f16x8*)&KT[eoff + ef*16 + li][lg*8];
    #pragma unroll
    for (int f2=0; f2<2; ++f2) bf[f2] = *(const f16x8*)&XT[ioff + f2*16 + li][lg*8];
    #pragma unroll
    for (int ef=0; ef<4; ++ef)
      #pragma unroll
      for (int f2=0; f2<2; ++f2)
        acc[ef][f2] = __builtin_amdgcn_mfma_f32_16x16x32_f16(af[ef], bf[f2], acc[ef][f2], 0,0,0);
  }

  float ps[2] = {0,0}, pn[2] = {0,0};
  #pragma unroll
  for (int ef=0; ef<4; ++ef){
    #pragma unroll
    for (int r=0;r<4;r++){
      int e = eoff + ef*16 + lg*4 + r;
      float as_e = attn_s[h*DH + e];
      float an_e = attn_n[h*DH + e];
      #pragma unroll
      for (int f2=0; f2<2; ++f2){
        int irow = i0 + ioff + f2*16 + li;
        float v = acc[ef][f2][r];
        featsT[(h*DH + e)*NN + irow] = (_Float16)v;
        ps[f2] += v*as_e; pn[f2] += v*an_e;
      }
    }
  }
  #pragma unroll
  for (int f2=0; f2<2; ++f2){
    ps[f2] += __shfl_xor(ps[f2], 16); ps[f2] += __shfl_xor(ps[f2], 32);
    pn[f2] += __shfl_xor(pn[f2], 16); pn[f2] += __shfl_xor(pn[f2], 32);
  }
  if (lane < 16){
    red_s[w>>1][w&1][0][lane] = ps[0]; red_s[w>>1][w&1][1][lane] = ps[1];
    red_n[w>>1][w&1][0][lane] = pn[0]; red_n[w>>1][w&1][1][lane] = pn[1];
  }
  __syncthreads();
  if (t < 64){
    int ih = t>>5, fb = (t>>4)&1, l2 = t&15;
    a_s[h*NN + i0 + t] = red_s[0][ih][fb][l2] + red_s[1][ih][fb][l2];
    a_n[h*NN + i0 + t] = red_n[0][ih][fb][l2] + red_n[1][ih][fb][l2];
  }
}

// K2: Amax[h] = max_j a_n[h][j]; EA=exp(an), GA=exp(0.2*an) tables (f16)
__global__ void k_amax(const float* __restrict__ a_n, float* __restrict__ Amax,
                       _Float16* __restrict__ EA_g, _Float16* __restrict__ GA_g){
  int h = blockIdx.x, t = threadIdx.x;
  float m = -3.4e38f;
  for (int i=t; i<NN; i+=256){
    float v = a_n[h*NN+i];
    m = fmaxf(m, v);
    EA_g[h*NN+i] = (_Float16)__builtin_exp2f(v*L2E);
    GA_g[h*NN+i] = (_Float16)__builtin_exp2f(0.2f*v*L2E);
  }
  #pragma unroll
  for (int s=1; s<64; s<<=1) m = fmaxf(m, __shfl_xor(m, s));
  __shared__ float sm[4];
  if ((t&63)==0) sm[t>>6] = m;
  __syncthreads();
  if (t==0) Amax[h] = fmaxf(fmaxf(sm[0],sm[1]), fmaxf(sm[2],sm[3]));
}

// K3: barrier-free PV. Block = 32 rows x 1 head; 4 waves each own a private
// 1024-col j-quarter with private 2x8KB LDS ft buffers synced by per-wave
// counted vmcnt (12 VMEM ops issued per iter -> vmcnt(12)). No s_barrier in
// the loop. Full j per block => denominator + divide + bias fused in epilogue.
__global__ __launch_bounds__(256, 2) void k_pv(
    const unsigned int* __restrict__ bmg, const _Float16* __restrict__ featsT,
    const float* __restrict__ a_s, const float* __restrict__ Amax,
    const _Float16* __restrict__ EA_g, const _Float16* __restrict__ GA_g,
    const float* __restrict__ bias, float* __restrict__ out)
{
  const int ib = blockIdx.x, h = blockIdx.y;
  const int i0 = ib*32;
  const int t = threadIdx.x, w = t>>6, lane = t&63;
  const int lg = lane>>4, li = lane&15;
  const int j0 = w*1024;                 // wave-private j-quarter

  __shared__ _Float16 ft[4][2][4096];    // 64 KB: [wave][dbuf][128e x 32j]
  __shared__ float dred[4][32];

  const int r0 = li, r1 = li + 16;
  const float am = Amax[h];
  const float as0 = a_s[h*NN + i0 + r0];
  const float as1 = a_s[h*NN + i0 + r1];
  const float m0 = leaky(as0 + am), m1 = leaky(as1 + am);
  const float E0f = __builtin_exp2f((as0 - m0)*L2E);
  const float G0f = __builtin_exp2f((0.2f*as0 - m0)*L2E);
  const float E1f = __builtin_exp2f((as1 - m1)*L2E);
  const float G1f = __builtin_exp2f((0.2f*as1 - m1)*L2E);
  f16x2 E0p; E0p[0]=E0p[1]=(_Float16)E0f;
  f16x2 G0p; G0p[0]=G0p[1]=(_Float16)G0f;
  f16x2 E1p; E1p[0]=E1p[1]=(_Float16)E1f;
  f16x2 G1p; G1p[0]=G1p[1]=(_Float16)G1f;

  const _Float16* EAh = EA_g + h*NN + j0;
  const _Float16* GAh = GA_g + h*NN + j0;
  const unsigned* bm0p = bmg + (size_t)(i0+r0)*(NN/32) + (j0>>5);
  const unsigned* bm1p = bmg + (size_t)(i0+r1)*(NN/32) + (j0>>5);

  // per-wave ft staging: linear LDS dest (HW adds lane*16B), pre-swizzled src col
  auto STAGE = [&](int b, int js){
    #pragma unroll
    for (int q=0;q<8;q++){
      int e = q*16 + (lane>>2);
      int l = (lane&3) ^ ((lane>>3)&3);
      __builtin_amdgcn_global_load_lds(
          (const __attribute__((address_space(1))) void*)(featsT + (size_t)(h*DH + e)*NN + j0 + js*32 + l*8),
          (__attribute__((address_space(3))) void*)(&ft[w][b][q*512]), 16, 0, 0);
    }
  };

  // prologue: issue js=0's full set (2 EA/GA + 2 bm + 8 stage = 12 VMEM ops)
  uint4 eaC = *(const uint4*)(EAh + lg*8);
  uint4 gaC = *(const uint4*)(GAh + lg*8);
  unsigned b0C = bm0p[0], b1C = bm1p[0];
  STAGE(0, 0);

  f32x4 acc0[8] = {}, acc1[8] = {};
  f32x4 accd0 = {}, accd1 = {};
  f16x8 ones;
  #pragma unroll
  for (int q=0;q<8;q++) ones[q] = (_Float16)1.0f;

  const int slot = lg ^ ((li>>1)&3);
  int buf = 0;

  for (int js=0; js<32; ++js){
    const int jsn = js+1 < 32 ? js+1 : 31;    // clamped dup keeps vmcnt cadence
    uint4 eaN = *(const uint4*)(EAh + jsn*32 + lg*8);
    uint4 gaN = *(const uint4*)(GAh + jsn*32 + lg*8);
    unsigned b0N = bm0p[jsn], b1N = bm1p[jsn];
    STAGE(buf^1, jsn);
    __builtin_amdgcn_sched_barrier(0);
    asm volatile("s_waitcnt vmcnt(12)" ::: "memory");  // js's 12 ops retired
    __builtin_amdgcn_sched_barrier(0);

    // af-gen (packed f16): W = max(Ei*EA, Gi*GA) & adjacency bit
    union { uint4 u; f16x2 p[4]; } ea, ga;
    ea.u = eaC; ga.u = gaC;
    union { f16x8 v; f16x2 p[4]; } af0u, af1u;
    const int sh = lg*8;
    #pragma unroll
    for (int p=0;p<4;p++){
      f16x2 w0 = h2max(E0p*ea.p[p], G0p*ga.p[p]);
      f16x2 w1 = h2max(E1p*ea.p[p], G1p*ga.p[p]);
      unsigned bb0 = b0C >> (sh + 2*p);
      unsigned bb1 = b1C >> (sh + 2*p);
      w0[0] = (bb0&1u) ? w0[0] : (_Float16)0;
      w0[1] = (bb0&2u) ? w0[1] : (_Float16)0;
      w1[0] = (bb1&1u) ? w1[0] : (_Float16)0;
      w1[1] = (bb1&2u) ? w1[1] : (_Float16)0;
      af0u.p[p] = w0; af1u.p[p] = w1;
    }
    f16x8 af0 = af0u.v, af1 = af1u.v;

    __builtin_amdgcn_s_setprio(1);
    #pragma unroll
    for (int ef=0; ef<8; ++ef){
      f16x8 bfr = *(const f16x8*)&ft[w][buf][(ef*16+li)*32 + slot*8];
      acc0[ef] = __builtin_amdgcn_mfma_f32_16x16x32_f16(af0, bfr, acc0[ef], 0,0,0);
      acc1[ef] = __builtin_amdgcn_mfma_f32_16x16x32_f16(af1, bfr, acc1[ef], 0,0,0);
    }
    accd0 = __builtin_amdgcn_mfma_f32_16x16x32_f16(af0, ones, accd0, 0,0,0);
    accd1 = __builtin_amdgcn_mfma_f32_16x16x32_f16(af1, ones, accd1, 0,0,0);
    __builtin_amdgcn_s_setprio(0);

    eaC = eaN; gaC = gaN; b0C = b0N; b1C = b1N; buf ^= 1;
  }

  // epilogue: drain tail stages, dump per-wave partials into own ft region
  __builtin_amdgcn_sched_barrier(0);
  asm volatile("s_waitcnt vmcnt(0)" ::: "memory");
  __builtin_amdgcn_sched_barrier(0);
  {
    float* red = (float*)&ft[w][0][0];        // 16 KB = [32 rows][128 e] f32
    #pragma unroll
    for (int ef=0; ef<8; ++ef)
      #pragma unroll
      for (int r=0;r<4;r++){
        red[(lg*4+r)*128 + ef*16 + li]      = acc0[ef][r];
        red[(16+lg*4+r)*128 + ef*16 + li]   = acc1[ef][r];
      }
    if (li == 0){
      *(f32x4*)&dred[w][lg*4]      = accd0;
      *(f32x4*)&dred[w][16+lg*4]   = accd1;
    }
  }
  __syncthreads();
  // cross-wave reduce + divide + bias + store
  {
    const int i = t>>3, c0 = (t&7)*16;
    float den = dred[0][i] + dred[1][i] + dred[2][i] + dred[3][i];
    float inv = 1.f/den;
    #pragma unroll
    for (int s=0;s<4;s++){
      f32x4 v = {};
      #pragma unroll
      for (int wq=0;wq<4;wq++){
        const float* rw = (const float*)&ft[wq][0][0];
        v += *(const f32x4*)&rw[i*128 + c0 + s*4];
      }
      f32x4 b4 = *(const f32x4*)&bias[h*DH + c0 + s*4];
      f32x4 o;
      o[0]=v[0]*inv+b4[0]; o[1]=v[1]*inv+b4[1];
      o[2]=v[2]*inv+b4[2]; o[3]=v[3]*inv+b4[3];
      *(f32x4*)&out[(size_t)(i0+i)*(NH*DH) + h*DH + c0 + s*4] = o;
    }
  }
}

extern "C" void kernel_launch(void* const* d_in, const int* in_sizes, int n_in,
                              void* d_out, int out_size, void* d_ws, size_t ws_size,
                              hipStream_t stream)
{
  const float* adj   = (const float*)d_in[0];
  const float* X     = (const float*)d_in[1];
  const float* Kw    = (const float*)d_in[2];
  const float* bias  = (const float*)d_in[3];
  const float* atn_s = (const float*)d_in[4];
  const float* atn_n = (const float*)d_in[5];
  float* out = (float*)d_out;

  char* ws = (char*)d_ws;
  _Float16* featsT = (_Float16*)ws;                            // 4 MB
  unsigned int* bmg = (unsigned int*)(ws + ((size_t)4<<20));   // 2 MB
  float* a_s  = (float*)(ws + (size_t)6*1024*1024);            // 64 KB
  float* a_n  = a_s + NH*NN;                                   // 64 KB
  float* Amax = a_n + NH*NN;                                   // 256 B slot
  _Float16* EA_g = (_Float16*)(Amax + 64);                     // 32 KB
  _Float16* GA_g = EA_g + NH*NN;                               // 32 KB

  hipLaunchKernelGGL(k_pack, dim3(2048), dim3(256), 0, stream, adj, bmg);
  hipLaunchKernelGGL(k_gemm1, dim3(64,4), dim3(256), 0, stream,
                     X, Kw, atn_s, atn_n, featsT, a_s, a_n);
  hipLaunchKernelGGL(k_amax, dim3(4), dim3(256), 0, stream, a_n, Amax, EA_g, GA_g);
  hipLaunchKernelGGL(k_pv, dim3(128,4), dim3(256), 0, stream,
                     bmg, featsT, a_s, Amax, EA_g, GA_g, bias, out);
}

// Round 12
// 78.746 us; speedup vs baseline: 1.0972x; 1.0972x over previous
//
#include <hip/hip_runtime.h>

#define NN 4096
#define DIN 512
#define DH 128
#define NH 4
#define JC 1024
#define NJC (NN/JC)   // 4
#define L2E 1.44269504f

typedef float f32x4 __attribute__((ext_vector_type(4)));
typedef _Float16 f16x8 __attribute__((ext_vector_type(8)));
typedef _Float16 f16x4 __attribute__((ext_vector_type(4)));
typedef _Float16 f16x2 __attribute__((ext_vector_type(2)));

__device__ __forceinline__ float leaky(float x){ return x > 0.f ? x : 0.2f*x; }

// K0: pack adjacency (0/1 f32) -> bitmask. Coalesced f32x4 loads, LDS nibble pack.
__global__ __launch_bounds__(256) void k_pack(
    const float* __restrict__ adj, unsigned int* __restrict__ bmg)
{
  __shared__ unsigned char nib[2][256];
  const int t = threadIdx.x;
  const size_t base = (size_t)blockIdx.x * 8192;
  #pragma unroll
  for (int it=0; it<8; ++it){
    const size_t fb = base + it*1024;
    f32x4 v = *(const f32x4*)&adj[fb + t*4];
    unsigned nb = (v[0]>0.5f?1u:0u)|(v[1]>0.5f?2u:0u)|(v[2]>0.5f?4u:0u)|(v[3]>0.5f?8u:0u);
    const int buf = it&1;
    nib[buf][t] = (unsigned char)nb;
    __syncthreads();
    if (t < 32){
      unsigned long long x = *(const unsigned long long*)&nib[buf][t*8];
      x &= 0x0F0F0F0F0F0F0F0FULL;
      x = (x | (x>>4))  & 0x00FF00FF00FF00FFULL;
      x = (x | (x>>8))  & 0x0000FFFF0000FFFFULL;
      x = (x | (x>>16));
      bmg[fb/32 + t] = (unsigned int)x;
    }
  }
}

// K1: featsT[h][e][i] = sum_d X[i][d]*Kw[h][d][e]  (f16 out) + a_s/a_n row dots
__global__ __launch_bounds__(256) void k_gemm1(
    const float* __restrict__ X, const float* __restrict__ Kw,
    const float* __restrict__ attn_s, const float* __restrict__ attn_n,
    _Float16* __restrict__ featsT, float* __restrict__ a_s, float* __restrict__ a_n)
{
  const int it = blockIdx.x, h = blockIdx.y;
  const int i0 = it*64;
  const int t = threadIdx.x, w = t>>6, lane = t&63;
  const int eoff = (w>>1)*64, ioff = (w&1)*32;
  const int lg = lane>>4, li = lane&15;

  __shared__ _Float16 KT[128][40];
  __shared__ _Float16 XT[64][40];
  __shared__ float red_s[2][2][2][16];
  __shared__ float red_n[2][2][2][16];

  f32x4 acc[4][2] = {};

  for (int ks=0; ks<16; ++ks){
    const int d0 = ks*32;
    __syncthreads();
    #pragma unroll
    for (int q=0;q<4;q++){
      int f = t + 256*q;
      int e = f & 127, dg = (f>>7)*4;
      f16x4 hv;
      #pragma unroll
      for (int k=0;k<4;k++)
        hv[k] = (_Float16)Kw[(h*DIN + d0 + dg + k)*DH + e];
      *(f16x4*)&KT[e][dg] = hv;
    }
    #pragma unroll
    for (int q=0;q<2;q++){
      int f = t + 256*q;
      int i = f>>3, s = (f&7)*4;
      f32x4 v = *(const f32x4*)&X[(i0+i)*DIN + d0 + s];
      f16x4 hv; hv[0]=(_Float16)v[0]; hv[1]=(_Float16)v[1];
      hv[2]=(_Float16)v[2]; hv[3]=(_Float16)v[3];
      *(f16x4*)&XT[i][s] = hv;
    }
    __syncthreads();
    f16x8 af[4], bf[2];
    #pragma unroll
    for (int ef=0; ef<4; ++ef) af[ef] = *(const f16x8*)&KT[eoff + ef*16 + li][lg*8];
    #pragma unroll
    for (int f2=0; f2<2; ++f2) bf[f2] = *(const f16x8*)&XT[ioff + f2*16 + li][lg*8];
    #pragma unroll
    for (int ef=0; ef<4; ++ef)
      #pragma unroll
      for (int f2=0; f2<2; ++f2)
        acc[ef][f2] = __builtin_amdgcn_mfma_f32_16x16x32_f16(af[ef], bf[f2], acc[ef][f2], 0,0,0);
  }

  float ps[2] = {0,0}, pn[2] = {0,0};
  #pragma unroll
  for (int ef=0; ef<4; ++ef){
    #pragma unroll
    for (int r=0;r<4;r++){
      int e = eoff + ef*16 + lg*4 + r;
      float as_e = attn_s[h*DH + e];
      float an_e = attn_n[h*DH + e];
      #pragma unroll
      for (int f2=0; f2<2; ++f2){
        int irow = i0 + ioff + f2*16 + li;
        float v = acc[ef][f2][r];
        featsT[(h*DH + e)*NN + irow] = (_Float16)v;
        ps[f2] += v*as_e; pn[f2] += v*an_e;
      }
    }
  }
  #pragma unroll
  for (int f2=0; f2<2; ++f2){
    ps[f2] += __shfl_xor(ps[f2], 16); ps[f2] += __shfl_xor(ps[f2], 32);
    pn[f2] += __shfl_xor(pn[f2], 16); pn[f2] += __shfl_xor(pn[f2], 32);
  }
  if (lane < 16){
    red_s[w>>1][w&1][0][lane] = ps[0]; red_s[w>>1][w&1][1][lane] = ps[1];
    red_n[w>>1][w&1][0][lane] = pn[0]; red_n[w>>1][w&1][1][lane] = pn[1];
  }
  __syncthreads();
  if (t < 64){
    int ih = t>>5, fb = (t>>4)&1, l2 = t&15;
    a_s[h*NN + i0 + t] = red_s[0][ih][fb][l2] + red_s[1][ih][fb][l2];
    a_n[h*NN + i0 + t] = red_n[0][ih][fb][l2] + red_n[1][ih][fb][l2];
  }
}

// K2: Amax[h] = max_j a_n[h][j]; EA=exp(an), GA=exp(0.2*an) tables (f16)
__global__ void k_amax(const float* __restrict__ a_n, float* __restrict__ Amax,
                       _Float16* __restrict__ EA_g, _Float16* __restrict__ GA_g){
  int h = blockIdx.x, t = threadIdx.x;
  float m = -3.4e38f;
  for (int i=t; i<NN; i+=256){
    float v = a_n[h*NN+i];
    m = fmaxf(m, v);
    EA_g[h*NN+i] = (_Float16)__builtin_exp2f(v*L2E);
    GA_g[h*NN+i] = (_Float16)__builtin_exp2f(0.2f*v*L2E);
  }
  #pragma unroll
  for (int s=1; s<64; s<<=1) m = fmaxf(m, __shfl_xor(m, s));
  __shared__ float sm[4];
  if ((t&63)==0) sm[t>>6] = m;
  __syncthreads();
  if (t==0) Amax[h] = fmaxf(fmaxf(sm[0],sm[1]), fmaxf(sm[2],sm[3]));
}

// K3: 16x16x32 PV, e-split waves. Block = 128 rows x 1024 cols x 1 head;
// 4 waves = 2 row-groups(64) x 2 e-halves(64): 4 ds_read_b128 serve 16 product
// MFMAs. R7-proven sync: vmcnt(2) -> s_barrier -> STAGE(js+2). EA/GA f16 in LDS.
__global__ __launch_bounds__(256, 2) void k_pv(
    const unsigned int* __restrict__ bmg, const _Float16* __restrict__ featsT,
    const float* __restrict__ a_s, const float* __restrict__ Amax,
    const _Float16* __restrict__ EA_g, const _Float16* __restrict__ GA_g,
    _Float16* __restrict__ Opart, float* __restrict__ Dpart)
{
  const int it = blockIdx.x, h = blockIdx.y, jcI = blockIdx.z;
  const int i0 = it*128, j0 = jcI*JC;
  const int t = threadIdx.x, w = t>>6, lane = t&63;
  const int lg = lane>>4, li = lane&15;
  const int rg = w&1, eh = w>>1;

  __shared__ _Float16 ft[3][128*32];        // 24 KB, [e][32j] 64B rows, slot-swizzled
  __shared__ _Float16 ea_s[JC], ga_s[JC];   // 4 KB
  __shared__ unsigned char bm_s[128][144];  // 18 KB

  // one-time staging: EA/GA (f16, 2KB each; 128 threads x 16B each)
  if (t < 128){
    __builtin_amdgcn_global_load_lds(
        (const __attribute__((address_space(1))) void*)(EA_g + h*NN + j0 + t*8),
        (__attribute__((address_space(3))) void*)(&ea_s[t*8]), 16, 0, 0);
  } else {
    __builtin_amdgcn_global_load_lds(
        (const __attribute__((address_space(1))) void*)(GA_g + h*NN + j0 + (t-128)*8),
        (__attribute__((address_space(3))) void*)(&ga_s[(t-128)*8]), 16, 0, 0);
  }
  // bitmask: 128 rows x 128 B = 1024 uint4 (4/thread)
  #pragma unroll
  for (int p=0;p<4;p++){
    int idx = p*256 + t;
    int r = idx>>3, c = idx&7;
    uint4 v = *(const uint4*)((const char*)bmg + (size_t)(i0+r)*(NN/8) + jcI*(JC/8) + c*16);
    *(uint4*)&bm_s[r][c*16] = v;
  }

  // per-frag row constants (frag f covers rows rg*64 + f*16 + li)
  const float am = Amax[h];
  f16x2 Epk[4], Gpk[4];
  #pragma unroll
  for (int f=0;f<4;f++){
    float asf = a_s[h*NN + i0 + rg*64 + f*16 + li];
    float mf = leaky(asf + am);
    Epk[f][0] = Epk[f][1] = (_Float16)__builtin_exp2f((asf - mf)*L2E);
    Gpk[f][0] = Gpk[f][1] = (_Float16)__builtin_exp2f((0.2f*asf - mf)*L2E);
  }

  // ft staging: linear LDS dest; source col pre-swizzled with f(e)=(e^(e>>2))&3
  auto STAGE = [&](int buf, int js){
    #pragma unroll
    for (int q=0;q<2;q++){
      int idx = q*256 + t;
      int e = idx>>2, p = idx&3;
      int l = p ^ ((e ^ (e>>2)) & 3);
      __builtin_amdgcn_global_load_lds(
          (const __attribute__((address_space(1))) void*)(featsT + (size_t)(h*DH + e)*NN + j0 + js*32 + l*8),
          (__attribute__((address_space(3))) void*)(&ft[buf][idx*8]), 16, 0, 0);
    }
  };

  STAGE(0, 0);
  STAGE(1, 1);
  __syncthreads();   // one-time full drain (ea/ga/bm/ft0/ft1)

  f32x4 acc[4][4] = {};
  f32x4 accd[4] = {};
  f16x8 ones;
  #pragma unroll
  for (int q=0;q<8;q++) ones[q] = (_Float16)1.0f;

  const int fsw = (li ^ (li>>2)) & 3;       // read-side swizzle term
  const int slot = lg ^ fsw;

  for (int js=0; js<32; ++js){
    asm volatile("s_waitcnt vmcnt(2)" ::: "memory");   // tile js retired
    __builtin_amdgcn_s_barrier();
    { int nst = js+2 < 32 ? js+2 : 31; STAGE((js+2)%3, nst); }  // after barrier: safe

    const int cur = js%3;
    union {f16x8 v; f16x2 p[4];} ea, ga;
    ea.v = *(const f16x8*)&ea_s[js*32 + lg*8];
    ga.v = *(const f16x8*)&ga_s[js*32 + lg*8];

    f16x8 bfr[4];
    #pragma unroll
    for (int ef=0; ef<4; ++ef){
      int row = eh*64 + ef*16 + li;
      bfr[ef] = *(const f16x8*)&ft[cur][row*32 + slot*8];
    }

    f16x8 af[4];
    #pragma unroll
    for (int f=0; f<4; ++f){
      unsigned b = (*(const unsigned*)&bm_s[rg*64 + f*16 + li][js*4]) >> (lg*8);
      union {f16x8 v; f16x2 p[4];} A;
      #pragma unroll
      for (int p2=0; p2<4; ++p2){
        f16x2 wv = __builtin_elementwise_max(Epk[f]*ea.p[p2], Gpk[f]*ga.p[p2]);
        int mlo = ((int)(b << (31-2*p2))) >> 31;
        int mhi = ((int)(b << (30-2*p2))) >> 31;
        unsigned m = ((unsigned)mlo & 0xFFFFu) | ((unsigned)mhi & 0xFFFF0000u);
        A.p[p2] = __builtin_bit_cast(f16x2,
                    (unsigned)(__builtin_bit_cast(unsigned, wv) & m));
      }
      af[f] = A.v;
    }

    __builtin_amdgcn_s_setprio(1);
    #pragma unroll
    for (int f=0; f<4; ++f){
      #pragma unroll
      for (int ef=0; ef<4; ++ef)
        acc[f][ef] = __builtin_amdgcn_mfma_f32_16x16x32_f16(af[f], bfr[ef], acc[f][ef], 0,0,0);
      accd[f] = __builtin_amdgcn_mfma_f32_16x16x32_f16(af[f], ones, accd[f], 0,0,0);
    }
    __builtin_amdgcn_s_setprio(0);
  }

  // epilogue: proven C layout col=li, row=lg*4+r
  const size_t chb = (size_t)(jcI*4 + h)*NN;
  #pragma unroll
  for (int f=0; f<4; ++f){
    const int rbase = i0 + rg*64 + f*16;
    if (li == 0 && eh == 0)
      *(f32x4*)&Dpart[chb + rbase + lg*4] = accd[f];
    #pragma unroll
    for (int ef=0; ef<4; ++ef)
      #pragma unroll
      for (int r=0; r<4; ++r)
        Opart[(size_t)(chb + rbase + lg*4 + r)*DH + eh*64 + ef*16 + li]
            = (_Float16)acc[f][ef][r];
  }
}

// K4: out[i][h*128+e] = sum_jc Opart / sum_jc Dpart + bias
__global__ __launch_bounds__(256) void k_out(
    const _Float16* __restrict__ Opart, const float* __restrict__ Dpart,
    const float* __restrict__ bias, float* __restrict__ out)
{
  int gid = blockIdx.x*256 + threadIdx.x;
  int base = gid*4;
  int i = base >> 9;
  int he = base & 511;
  int h = he >> 7;
  int e = he & 127;
  float n0=0,n1=0,n2=0,n3=0, den=0;
  #pragma unroll
  for (int jc=0; jc<NJC; ++jc){
    int ch = (jc*4+h)*NN + i;
    f16x4 v = *(const f16x4*)(Opart + (size_t)ch*DH + e);
    n0 += (float)v[0]; n1 += (float)v[1]; n2 += (float)v[2]; n3 += (float)v[3];
    den += Dpart[ch];
  }
  float inv = 1.f/den;
  f32x4 b4 = *(const f32x4*)&bias[he];
  f32x4 o; o[0]=n0*inv+b4[0]; o[1]=n1*inv+b4[1]; o[2]=n2*inv+b4[2]; o[3]=n3*inv+b4[3];
  *(f32x4*)&out[base] = o;
}

extern "C" void kernel_launch(void* const* d_in, const int* in_sizes, int n_in,
                              void* d_out, int out_size, void* d_ws, size_t ws_size,
                              hipStream_t stream)
{
  const float* adj   = (const float*)d_in[0];
  const float* X     = (const float*)d_in[1];
  const float* Kw    = (const float*)d_in[2];
  const float* bias  = (const float*)d_in[3];
  const float* atn_s = (const float*)d_in[4];
  const float* atn_n = (const float*)d_in[5];
  float* out = (float*)d_out;

  char* ws = (char*)d_ws;
  _Float16* featsT = (_Float16*)ws;                            // 4 MB
  unsigned int* bmg = (unsigned int*)(ws + ((size_t)4<<20));   // 2 MB
  float* a_s  = (float*)(ws + (size_t)6*1024*1024);            // 64 KB
  float* a_n  = a_s + NH*NN;                                   // 64 KB
  float* Amax = a_n + NH*NN;                                   // 256 B slot
  _Float16* EA_g = (_Float16*)(Amax + 64);                     // 32 KB
  _Float16* GA_g = EA_g + NH*NN;                               // 32 KB
  float* Dpart = (float*)(GA_g + NH*NN);                       // 256 KB
  _Float16* Opart = (_Float16*)(Dpart + NJC*NH*NN);            // 16 MB

  hipLaunchKernelGGL(k_pack, dim3(2048), dim3(256), 0, stream, adj, bmg);
  hipLaunchKernelGGL(k_gemm1, dim3(64,4), dim3(256), 0, stream,
                     X, Kw, atn_s, atn_n, featsT, a_s, a_n);
  hipLaunchKernelGGL(k_amax, dim3(4), dim3(256), 0, stream, a_n, Amax, EA_g, GA_g);
  hipLaunchKernelGGL(k_pv, dim3(32,4,NJC), dim3(256), 0, stream,
                     bmg, featsT, a_s, Amax, EA_g, GA_g, Opart, Dpart);
  hipLaunchKernelGGL(k_out, dim3(2048), dim3(256), 0, stream,
                     Opart, Dpart, bias, out);
}